// Round 1
// 168.674 us; speedup vs baseline: 1.0391x; 1.0391x over previous
//
#include <hip/hip_runtime.h>

// ALSTM: adaptive-computation-time LSTM (halts at t=1 for this data; exact
// for general n).
// R12 restructure (theory: phase-serialized latency, not BW/VALU):
//  - ONE upfront issue burst: x,h0,c0,biases,w_halt,b_out,W_out(regs),
//    all 16 W_ih float4, W_hh rows 0-1; then convert(r) || issue(r+2)
//    pipeline for W_hh. VMEM queue never drains between phases.
//  - t=0 gate matvec FUSED into the fp32 W_hh conversion pass (fp32*fp32,
//    also better absmax than the old bf16*bf16 t=0 path).
//  - sync #3 DELETED: full hbar[2048] accumulated in LDS per block (each
//    block already reads full h_{t+1} for hpk staging); epilogue dots
//    register-resident W_out rows against LDS hbar. No hbar_g broadcast.
//  - s_sleep(1) in barrier spin loops (don't steal fabric BW from
//    straggler blocks still streaming).

#define HID    2048
#define INS    1024
#define OUTS   1024
#define MSTEPS 100
#define NBLK   256
#define NTHR   512
#define NWAVE  8
#define JPB    8      // hidden units owned per block (256*8 = 2048)
#define RPB    32     // gate rows per block (4 gates * JPB)
#define SLOTF  16     // floats per sync slot (64 B)

typedef unsigned long long u64;
typedef unsigned int u32;

__device__ __forceinline__ float wave_allreduce(float v) {
    #pragma unroll
    for (int off = 32; off > 0; off >>= 1)
        v += __shfl_xor(v, off, 64);
    return v;  // all lanes hold the sum
}

__device__ __forceinline__ u32 bf16_2(float a, float b) {   // RNE pack
    u32 ua = __float_as_uint(a), ub = __float_as_uint(b);
    ua = (ua + 0x7fffu + ((ua >> 16) & 1u)) >> 16;
    ub = (ub + 0x7fffu + ((ub >> 16) & 1u)) >> 16;
    return ua | (ub << 16);
}
__device__ __forceinline__ float blo(u32 u) { return __uint_as_float(u << 16); }
__device__ __forceinline__ float bhi(u32 u) { return __uint_as_float(u & 0xffff0000u); }

__device__ __forceinline__ u64 pack_tag(unsigned tag, float v) {
    return ((u64)tag << 32) | (u64)__float_as_uint(v);
}
__device__ __forceinline__ u64 aload(const u64* p) {
    return __hip_atomic_load(p, __ATOMIC_RELAXED, __HIP_MEMORY_SCOPE_AGENT);
}
__device__ __forceinline__ void astore(u64* p, u64 v) {
    __hip_atomic_store(p, v, __ATOMIC_RELAXED, __HIP_MEMORY_SCOPE_AGENT);
}

// ws layout (floats): [0..4096) arrive slots (256 x 64B) | [4096..8192)
// mailboxes | [8192..10240) hbuf0 | [10240..12288) hbuf1.
// kernel_launch zeroes the first 32768 bytes each call.

__global__ __launch_bounds__(NTHR, 2) void alstm_kernel(
    const float* __restrict__ x,      const float* __restrict__ h0,
    const float* __restrict__ c0,     const float* __restrict__ W_ih,
    const float* __restrict__ b_ih,   const float* __restrict__ W_hh,
    const float* __restrict__ b_hh,   const float* __restrict__ w_halt,
    const float* __restrict__ b_halt, const float* __restrict__ W_out,
    const float* __restrict__ b_out,  float* __restrict__ out,
    float* __restrict__ ws)
{
    const int b    = blockIdx.x;
    const int tid  = threadIdx.x;
    const int wave = tid >> 6;
    const int lane = tid & 63;

    float* arrive = ws;                 // 256 x SLOTF floats
    float* mail   = ws + NBLK * SLOTF;
    float* hbuf0  = ws + 2 * NBLK * SLOTF;
    float* hbuf1  = hbuf0 + HID;

    __shared__ u32   whh_u[RPB * 1024];   // 128 KB: 32 rows x 2048 bf16
    __shared__ u32   hpk[HID / 2];        // 4 KB: h as packed bf16
    __shared__ float x_lds[INS];          // 4 KB
    __shared__ float hjoint[HID];         // 8 KB: h0 fp32, then hbar accum
    __shared__ float gate_lds[RPB];
    __shared__ float ihx_lds[RPB];
    __shared__ float red_lds[4];
    __shared__ float bcast_lds;
    __shared__ float psum[NWAVE];

    const int j_own = b * JPB + tid;      // valid when tid < JPB
    const int lr0   = 4 * wave;           // this wave's first gate row
    const int rbase = (lr0 >> 3) * HID + b * JPB + (lr0 & 7);

    #define SYNC_ROUND(tag_, part_, dot_) do {                                 \
        if (tid == 0) {                                                        \
            __threadfence();   /* wb: h stores reach coherence point */        \
            astore((u64*)(arrive + SLOTF * b), pack_tag((tag_), (part_)));     \
        }                                                                      \
        if (b == 0) {                                                          \
            float pf = 0.f;                                                    \
            if (tid < NBLK) {                                                  \
                u64 v = aload((u64*)(arrive + SLOTF * tid));                   \
                while ((unsigned)(v >> 32) != (unsigned)(tag_)) {              \
                    __builtin_amdgcn_s_sleep(1);                               \
                    v = aload((u64*)(arrive + SLOTF * tid));                   \
                }                                                              \
                pf = __uint_as_float((unsigned)v);                             \
            }                                                                  \
            float s = wave_allreduce(pf);                                      \
            if (lane == 0 && wave < 4) red_lds[wave] = s;                      \
            __syncthreads();                                                   \
            if (tid == 0)                                                      \
                bcast_lds = red_lds[0] + red_lds[1] + red_lds[2] + red_lds[3]; \
            __syncthreads();                                                   \
            if (tid < NBLK)                                                    \
                astore((u64*)(mail + SLOTF * tid), pack_tag((tag_), bcast_lds)); \
        }                                                                      \
        if (tid == 0) {                                                        \
            u64 v = aload((u64*)(mail + SLOTF * b));                           \
            while ((unsigned)(v >> 32) != (unsigned)(tag_)) {                  \
                __builtin_amdgcn_s_sleep(1);                                   \
                v = aload((u64*)(mail + SLOTF * b));                           \
            }                                                                  \
            bcast_lds = __uint_as_float((unsigned)v);                          \
            __threadfence();   /* inv: later plain reads see fresh data */     \
        }                                                                      \
        __syncthreads();                                                       \
        (dot_) = bcast_lds;                                                    \
    } while (0)

    #define ISSUE_ROW(BUF, RR) do {                                           \
        const float4* src_ = (const float4*)(W_hh + (size_t)(rbase + (RR)) * HID); \
        _Pragma("unroll")                                                      \
        for (int m = 0; m < 8; ++m) BUF[m] = src_[lane + 64 * m];              \
    } while (0)

    // convert one fp32 row to bf16 LDS + fused t=0 dot with fp32 h0 (hjoint)
    #define CONVROW(BUF, RR, GACC) do {                                       \
        u32* dst_ = whh_u + (lr0 + (RR)) * (HID / 2);                         \
        const float4* h4_ = (const float4*)hjoint;                            \
        _Pragma("unroll")                                                      \
        for (int m = 0; m < 8; ++m) {                                         \
            float4 w4 = BUF[m];                                               \
            dst_[2 * (lane + 64 * m)]     = bf16_2(w4.x, w4.y);               \
            dst_[2 * (lane + 64 * m) + 1] = bf16_2(w4.z, w4.w);               \
            float4 hv_ = h4_[lane + 64 * m];                                  \
            GACC += w4.x * hv_.x + w4.y * hv_.y + w4.z * hv_.z + w4.w * hv_.w;\
        }                                                                      \
    } while (0)

    // ---------------- upfront issue burst ----------------
    const float bh = b_halt[0];
    float2 xv  = ((const float2*)x)[tid];
    float4 h0v = ((const float4*)h0)[tid];
    float c_reg = (tid < JPB) ? c0[j_own]     : 0.f;
    float whv   = (tid < JPB) ? w_halt[j_own] : 0.f;
    float bo    = (tid < 4)   ? b_out[b * 4 + tid] : 0.f;
    float bsum = 0.f, wflg = 0.f;
    if (lane < 4) {
        const int lr = lr0 + lane;
        const int r  = (lr >> 3) * HID + b * JPB + (lr & 7);
        bsum = b_ih[r] + b_hh[r];
        wflg = W_ih[(size_t)r * (INS + 1)];
    }
    __builtin_amdgcn_sched_barrier(0);   // small loads pinned oldest

    // W_out rows for the epilogue: live in registers until the end.
    const int orow = b * 4 + (wave & 3);
    const int ohalf = wave >> 2;
    const float4* wrow = (const float4*)(W_out + (size_t)orow * HID) + ohalf * 256;
    float4 wo0 = wrow[lane], wo1 = wrow[lane + 64],
           wo2 = wrow[lane + 128], wo3 = wrow[lane + 192];

    // W_ih: all 16 float4 (4 rows x 4) issued now, consumed after x_lds sync
    const float*  wr_[4];
    const float4* wv_[4];
    int p0_[4];
    #pragma unroll
    for (int rr = 0; rr < 4; ++rr) {
        const int lr = lr0 + rr;
        const int r  = (lr >> 3) * HID + b * JPB + (lr & 7);
        wr_[rr] = W_ih + (size_t)r * (INS + 1) + 1;   // payload
        p0_[rr] = (4 - ((r + 1) & 3)) & 3;
        wv_[rr] = (const float4*)(wr_[rr] + p0_[rr]);
    }
    float4 iw0[4], iw1[4], iw2[4], iw3[4];
    #pragma unroll
    for (int ii = 0; ii < 4; ++ii) {
        const int i  = lane + 64 * ii;
        const int ic = (i < 255) ? i : 0;   // clamp; masked at accumulate
        iw0[ii] = wv_[0][ic];
        iw1[ii] = wv_[1][ic];
        iw2[ii] = wv_[2][ic];
        iw3[ii] = wv_[3][ic];
    }

    // W_hh rows 0,1 issued now; rows 2,3 pipelined behind converts.
    float4 wa[8], wb[8];
    ISSUE_ROW(wa, 0);
    ISSUE_ROW(wb, 1);
    __builtin_amdgcn_sched_barrier(0);   // keep the whole burst in flight

    // stage x + h0 (oldest loads -> waitcnt leaves the burst outstanding)
    ((float2*)x_lds)[tid]  = xv;
    ((float4*)hjoint)[tid] = h0v;        // hjoint = fp32 h0 for fused t=0 dot
    __syncthreads();

    // ---- ih dots: W_ih[:,1:]@x, 4 rows interleaved (loads long in flight) ----
    float a0 = 0.f, a1 = 0.f, a2 = 0.f, a3 = 0.f;
    #pragma unroll
    for (int ii = 0; ii < 4; ++ii) {
        const int   i   = lane + 64 * ii;
        const int   ic  = (i < 255) ? i : 0;
        const float msk = (i < 255) ? 1.f : 0.f;
        #pragma unroll
        for (int rr = 0; rr < 4; ++rr) {
            float4 w4 = (rr == 0) ? iw0[ii] : (rr == 1) ? iw1[ii]
                      : (rr == 2) ? iw2[ii] : iw3[ii];
            const int k = p0_[rr] + 4 * ic;
            float s = w4.x * x_lds[k]     + w4.y * x_lds[k + 1]
                    + w4.z * x_lds[k + 2] + w4.w * x_lds[k + 3];
            s *= msk;
            if      (rr == 0) a0 += s;
            else if (rr == 1) a1 += s;
            else if (rr == 2) a2 += s;
            else              a3 += s;
        }
    }
    // leftover 4 elements per row: lanes 0..3, one element each
    if (lane < 4) {
        #pragma unroll
        for (int rr = 0; rr < 4; ++rr) {
            const int p0 = p0_[rr];
            const int e  = (lane < p0) ? lane : 1020 + lane;
            float s = wr_[rr][e] * x_lds[e];
            if      (rr == 0) a0 += s;
            else if (rr == 1) a1 += s;
            else if (rr == 2) a2 += s;
            else              a3 += s;
        }
    }

    // ---- W_hh convert pipeline: bf16->LDS + fused fp32 t=0 dot ----
    float g0 = 0.f, g1 = 0.f, g2 = 0.f, g3 = 0.f;
    CONVROW(wa, 0, g0);  ISSUE_ROW(wa, 2);
    CONVROW(wb, 1, g1);  ISSUE_ROW(wb, 3);
    CONVROW(wa, 2, g2);
    CONVROW(wb, 3, g3);

    a0 = wave_allreduce(a0); a1 = wave_allreduce(a1);
    a2 = wave_allreduce(a2); a3 = wave_allreduce(a3);
    g0 = wave_allreduce(g0); g1 = wave_allreduce(g1);
    g2 = wave_allreduce(g2); g3 = wave_allreduce(g3);
    if (lane < 4) {
        float av = (lane == 0) ? a0 : (lane == 1) ? a1 : (lane == 2) ? a2 : a3;
        float gv = (lane == 0) ? g0 : (lane == 1) ? g1 : (lane == 2) ? g2 : g3;
        ihx_lds[lr0 + lane]  = av + bsum;                // reused every step
        gate_lds[lr0 + lane] = av + bsum + wflg + gv;    // t=0 gates (flag=1)
    }
    __syncthreads();                       // converts done + gate_lds ready
    ((float4*)hjoint)[tid] = make_float4(0.f, 0.f, 0.f, 0.f);  // hbar accum

    // ------------- recurrence -------------
    float h_reg = 0.f, cbar = 0.f;
    float csum = 0.f, r_halt = 0.f;
    int   n_halt = 0;
    for (int t = 0; t <= MSTEPS; ++t) {
        // gate_lds valid here (pre-loop sync for t=0; bottom sync for t>0)
        float part = 0.f;
        float* hdst = (t & 1) ? hbuf1 : hbuf0;
        if (tid < JPB) {
            float iv = gate_lds[0 * JPB + tid];
            float fv = gate_lds[1 * JPB + tid];
            float gv = gate_lds[2 * JPB + tid];
            float ov = gate_lds[3 * JPB + tid];
            iv = 1.f / (1.f + expf(-iv));
            fv = 1.f / (1.f + expf(-fv));
            gv = tanhf(gv);
            ov = 1.f / (1.f + expf(-ov));
            c_reg = fv * c_reg + iv * gv;
            h_reg = ov * tanhf(c_reg);
            hdst[j_own] = h_reg;
            part = h_reg * whv;
        }
        part += __shfl_down(part, 4, 64);
        part += __shfl_down(part, 2, 64);
        part += __shfl_down(part, 1, 64);

        float dotv;
        SYNC_ROUND(t + 1, part, dotv);

        float p = 1.f / (1.f + expf(-(dotv + bh)));
        float prev = csum;
        csum += p;
        bool  halt_now = (csum >= 1.f - 0.01f) || (t == MSTEPS);
        float wt = halt_now ? (1.f - prev) : p;

        // full h_{t+1}: one read serves hbar accumulation AND hpk staging
        float4 hv = ((const float4*)hdst)[tid];
        float4 hb = ((float4*)hjoint)[tid];      // own slot, no race
        hb.x += wt * hv.x; hb.y += wt * hv.y;
        hb.z += wt * hv.z; hb.w += wt * hv.w;
        ((float4*)hjoint)[tid] = hb;
        if (tid < JPB) cbar += wt * c_reg;
        if (halt_now) { n_halt = t; r_halt = 1.f - prev; break; }  // uniform

        hpk[2 * tid]     = bf16_2(hv.x, hv.y);
        hpk[2 * tid + 1] = bf16_2(hv.z, hv.w);
        __syncthreads();                         // hpk ready

        {   // W_hh @ h, bf16 x bf16 from LDS
            const uint4* hp = (const uint4*)hpk;
            float m0 = 0.f, m1 = 0.f, m2 = 0.f, m3 = 0.f;
            #pragma unroll
            for (int m = 0; m < 4; ++m) {
                uint4 hu = hp[lane + 64 * m];
                float h0a = blo(hu.x), h1a = bhi(hu.x);
                float h2a = blo(hu.y), h3a = bhi(hu.y);
                float h4a = blo(hu.z), h5a = bhi(hu.z);
                float h6a = blo(hu.w), h7a = bhi(hu.w);
                #pragma unroll
                for (int rr = 0; rr < 4; ++rr) {
                    const uint4* wp = (const uint4*)(whh_u + (lr0 + rr) * (HID / 2));
                    uint4 wu = wp[lane + 64 * m];
                    float s = blo(wu.x) * h0a + bhi(wu.x) * h1a
                            + blo(wu.y) * h2a + bhi(wu.y) * h3a
                            + blo(wu.z) * h4a + bhi(wu.z) * h5a
                            + blo(wu.w) * h6a + bhi(wu.w) * h7a;
                    if      (rr == 0) m0 += s;
                    else if (rr == 1) m1 += s;
                    else if (rr == 2) m2 += s;
                    else              m3 += s;
                }
            }
            m0 = wave_allreduce(m0); m1 = wave_allreduce(m1);
            m2 = wave_allreduce(m2); m3 = wave_allreduce(m3);
            if (lane < 4) {
                float mv = (lane == 0) ? m0 : (lane == 1) ? m1
                         : (lane == 2) ? m2 : m3;
                gate_lds[lr0 + lane] = ihx_lds[lr0 + lane] + mv;
            }
        }
        __syncthreads();                         // gate_lds ready for next t
    }

    // ------------- epilogue: no grid sync needed -------------
    __syncthreads();                             // hbar (hjoint) complete
    if (tid < JPB) {
        out[OUTS + j_own]       = hjoint[j_own];   // h_out
        out[OUTS + HID + j_own] = cbar;            // c_out
    }
    if (b == 0 && tid == 0) out[OUTS + 2 * HID] = (float)(n_halt + 1) + r_halt;

    // output = W_out @ hbar + b_out : W_out rows already in registers
    {
        const float4* hb4 = (const float4*)hjoint + ohalf * 256;
        float acc = 0.f;
        { float4 h4 = hb4[lane];       acc += wo0.x*h4.x + wo0.y*h4.y + wo0.z*h4.z + wo0.w*h4.w; }
        { float4 h4 = hb4[lane + 64];  acc += wo1.x*h4.x + wo1.y*h4.y + wo1.z*h4.z + wo1.w*h4.w; }
        { float4 h4 = hb4[lane + 128]; acc += wo2.x*h4.x + wo2.y*h4.y + wo2.z*h4.z + wo2.w*h4.w; }
        { float4 h4 = hb4[lane + 192]; acc += wo3.x*h4.x + wo3.y*h4.y + wo3.z*h4.z + wo3.w*h4.w; }
        acc = wave_allreduce(acc);
        if (lane == 0) psum[wave] = acc;
    }
    __syncthreads();
    if (tid < 4) out[b * 4 + tid] = psum[tid] + psum[tid + 4] + bo;

    #undef SYNC_ROUND
    #undef ISSUE_ROW
    #undef CONVROW
}

extern "C" void kernel_launch(void* const* d_in, const int* in_sizes, int n_in,
                              void* d_out, int out_size, void* d_ws, size_t ws_size,
                              hipStream_t stream) {
    const float* x      = (const float*)d_in[0];
    const float* h0     = (const float*)d_in[1];
    const float* c0     = (const float*)d_in[2];
    const float* W_ih   = (const float*)d_in[3];
    const float* b_ih   = (const float*)d_in[4];
    const float* W_hh   = (const float*)d_in[5];
    const float* b_hh   = (const float*)d_in[6];
    const float* w_halt = (const float*)d_in[7];
    const float* b_halt = (const float*)d_in[8];
    const float* W_out  = (const float*)d_in[9];
    const float* b_out  = (const float*)d_in[10];
    float* out = (float*)d_out;
    float* ws  = (float*)d_ws;

    // Zero arrive slots + mailboxes (ws is poisoned 0xAA by the harness).
    hipMemsetAsync(d_ws, 0, 32768, stream);

    alstm_kernel<<<dim3(NBLK), dim3(NTHR), 0, stream>>>(
        x, h0, c0, W_ih, b_ih, W_hh, b_hh, w_halt, b_halt, W_out, b_out,
        out, ws);
}